// Round 2
// baseline (325.517 us; speedup 1.0000x reference)
//
#include <hip/hip_runtime.h>

typedef __bf16 bf16x8 __attribute__((ext_vector_type(8)));
typedef float floatx4 __attribute__((ext_vector_type(4)));

#define DEVI __device__ __forceinline__

DEVI unsigned short f2bf(float f) {
  union { float f; unsigned u; } v; v.f = f;
  unsigned r = v.u + 0x7FFFu + ((v.u >> 16) & 1u);
  return (unsigned short)(r >> 16);
}

DEVI void gload_lds16(const void* g, void* l) {
  __builtin_amdgcn_global_load_lds((const __attribute__((address_space(1))) void*)g,
                                   (__attribute__((address_space(3))) void*)l,
                                   16, 0, 0);
}

// ---- transpose-convert x[B,512,2048] f32 -> xt[B,2048,512] bf16 ; z==16 slice does weight prep ----
__global__ __launch_bounds__(256) void k_transpose(
    const float* __restrict__ x, unsigned short* __restrict__ xt,
    const float* __restrict__ phi_w, const float* __restrict__ g_w,
    const float* __restrict__ theta_w, const float* __restrict__ W_w,
    const float* __restrict__ phi_b, const float* __restrict__ g_b,
    unsigned short* __restrict__ wpg, unsigned short* __restrict__ thw,
    unsigned short* __restrict__ ww, float* __restrict__ pgbias) {
  const int t = threadIdx.x;
  if (blockIdx.z == 16) {
    // weight prep, grid-stride over 256 blocks * 256 threads
    const int T0 = 512 * 512, T1 = T0 + 256 * 512, T2 = T1 + 512 * 256, T3 = T2 + 512;
    int base = (blockIdx.y * 32 + blockIdx.x) * 256 + t;
    for (int i = base; i < T3; i += 65536) {
      if (i < T0) {
        int o = i >> 9, c = i & 511;
        float v = (o < 256) ? phi_w[o * 512 + c] : g_w[(o - 256) * 512 + c];
        wpg[i] = f2bf(v);
      } else if (i < T1) {
        int j = i - T0; thw[j] = f2bf(theta_w[j]);
      } else if (i < T2) {
        int j = i - T1; ww[j] = f2bf(W_w[j]);
      } else {
        int o = i - T2; pgbias[o] = (o < 256) ? phi_b[o] : g_b[o - 256];
      }
    }
    return;
  }
  __shared__ float tile[64][65];
  const int b = blockIdx.z, c0 = blockIdx.y * 64, n0 = blockIdx.x * 64;
  const float* xb = x + (size_t)b * 512 * 2048;
#pragma unroll
  for (int i = 0; i < 16; ++i) {
    int lin = i * 256 + t;
    int lc = lin >> 6, ln = lin & 63;
    tile[lc][ln] = xb[(size_t)(c0 + lc) * 2048 + (n0 + ln)];
  }
  __syncthreads();
  unsigned short* xtb = xt + (size_t)b * 2048 * 512;
#pragma unroll
  for (int i = 0; i < 16; ++i) {
    int lin = i * 256 + t;
    int ln = lin >> 6, lc = lin & 63;
    xtb[(size_t)(n0 + ln) * 512 + (c0 + lc)] = f2bf(tile[lc][ln]);
  }
}

// ---- generic GEMM  C[i,j] = scale*sum_k A[i,k]B[j,k] (+bias); 4 waves, 128x128-ish tiles ----
// 1-D grid of 16*T blocks, lid == batch (mod 8)  -> batch pinned to XCD.
// EPI: 0 none, 1 +bias[row], 2 +bias[col]. BNS: atomic per-row sum/sumsq into bnsum[1024].
template <int BM, int BN, int EPI, bool BNS, int T, int NTX>
__global__ __launch_bounds__(256) void k_gemm(
    const unsigned short* __restrict__ A, const unsigned short* __restrict__ B,
    unsigned short* __restrict__ C, int N, int K,
    size_t sA, size_t sB, size_t sC,
    const float* __restrict__ bias, float scale, float* __restrict__ bnsum) {
  constexpr int WM = BM / 2, WN = BN / 2;
  constexpr int FM = WM / 16, FN = WN / 16;
  __shared__ __align__(16) __bf16 At[BM * 32];
  __shared__ __align__(16) __bf16 Bt[BN * 32];
  const int t = threadIdx.x;
  const int lid = blockIdx.x;
  const int b = (lid & 7) + 8 * ((lid >> 3) / T);
  const int tt = (lid >> 3) % T;
  const int col0 = (tt % NTX) * BN;
  const int row0 = (tt / NTX) * BM;
  const unsigned short* Az = A + (size_t)b * sA;
  const unsigned short* Bz = B + (size_t)b * sB;
  unsigned short* Cz = C + (size_t)b * sC;

  const int w = t >> 6, lane = t & 63;
  const int l16 = lane & 15, lq = lane >> 4;
  const int wrow0 = (w >> 1) * WM, wcol0 = (w & 1) * WN;

  floatx4 acc[FM][FN];
#pragma unroll
  for (int m = 0; m < FM; ++m)
#pragma unroll
    for (int n = 0; n < FN; ++n) acc[m][n] = (floatx4){0.f, 0.f, 0.f, 0.f};

  const int kt_end = K >> 5;
  for (int kt = 0; kt < kt_end; ++kt) {
    __syncthreads();
#pragma unroll
    for (int i = 0; i < BM * 4 / 256; ++i) {
      int ch = i * 256 + t;
      int r = ch >> 2, kq = ch & 3;
      gload_lds16(Az + (size_t)(row0 + r) * K + (kt << 5) + (kq << 3), &At[ch * 8]);
    }
#pragma unroll
    for (int i = 0; i < BN * 4 / 256; ++i) {
      int ch = i * 256 + t;
      int r = ch >> 2, kq = ch & 3;
      gload_lds16(Bz + (size_t)(col0 + r) * K + (kt << 5) + (kq << 3), &Bt[ch * 8]);
    }
    __syncthreads();

    bf16x8 af[FM], bq[FN];
#pragma unroll
    for (int m = 0; m < FM; ++m)
      af[m] = *(const bf16x8*)&At[(wrow0 + m * 16 + l16) * 32 + lq * 8];
#pragma unroll
    for (int n = 0; n < FN; ++n)
      bq[n] = *(const bf16x8*)&Bt[(wcol0 + n * 16 + l16) * 32 + lq * 8];
#pragma unroll
    for (int m = 0; m < FM; ++m)
#pragma unroll
      for (int n = 0; n < FN; ++n)
        acc[m][n] = __builtin_amdgcn_mfma_f32_16x16x32_bf16(af[m], bq[n], acc[m][n], 0, 0, 0);
  }

  float sv[FM][4], ssv[FM][4];
  if (BNS) {
#pragma unroll
    for (int m = 0; m < FM; ++m)
#pragma unroll
      for (int r = 0; r < 4; ++r) { sv[m][r] = 0.f; ssv[m][r] = 0.f; }
  }
#pragma unroll
  for (int m = 0; m < FM; ++m)
#pragma unroll
    for (int n = 0; n < FN; ++n) {
      int gc = col0 + wcol0 + n * 16 + l16;
      float bc = (EPI == 2) ? bias[gc] : 0.f;
#pragma unroll
      for (int r = 0; r < 4; ++r) {
        int gr = row0 + wrow0 + m * 16 + lq * 4 + r;
        float v = acc[m][n][r] * scale;
        if (EPI == 1) v += bias[gr];
        if (EPI == 2) v += bc;
        if (BNS) { sv[m][r] += v; ssv[m][r] += v * v; }
        Cz[(size_t)gr * N + gc] = f2bf(v);
      }
    }
  if (BNS) {
#pragma unroll
    for (int m = 0; m < FM; ++m)
#pragma unroll
      for (int r = 0; r < 4; ++r) {
        float s = sv[m][r], ss = ssv[m][r];
        s += __shfl_xor(s, 1); ss += __shfl_xor(ss, 1);
        s += __shfl_xor(s, 2); ss += __shfl_xor(ss, 2);
        s += __shfl_xor(s, 4); ss += __shfl_xor(ss, 4);
        s += __shfl_xor(s, 8); ss += __shfl_xor(ss, 8);
        if (l16 == 0) {
          int gr = row0 + wrow0 + m * 16 + lq * 4 + r;
          unsafeAtomicAdd(&bnsum[gr], s);
          unsafeAtomicAdd(&bnsum[512 + gr], ss);
        }
      }
  }
}

// ---- G3: amat_f32[b][c',c] += split-K partial of sum_n ph[c',n] g[c,n]; 256^2 tile, 8 waves ----
__global__ __launch_bounds__(512) void k_gemm_splitk(const unsigned short* __restrict__ phg,
                                                     float* __restrict__ amatf) {
  __shared__ __align__(16) __bf16 At[256 * 32];
  __shared__ __align__(16) __bf16 Bt[256 * 32];
  const int t = threadIdx.x;
  const int lid = blockIdx.x;              // 64 blocks: b%8 == lid%8
  const int b = (lid & 7) + 8 * (lid >> 5);
  const int split = (lid >> 3) & 3;
  const size_t sPG = (size_t)512 * 2048;
  const unsigned short* Az = phg + (size_t)b * sPG;                 // ph rows
  const unsigned short* Bz = Az + (size_t)256 * 2048;               // g rows
  const int w = t >> 6, lane = t & 63;
  const int l16 = lane & 15, lq = lane >> 4;
  const int wrow0 = (w >> 2) * 128, wcol0 = (w & 3) * 64;

  floatx4 acc[8][4];
#pragma unroll
  for (int m = 0; m < 8; ++m)
#pragma unroll
    for (int n = 0; n < 4; ++n) acc[m][n] = (floatx4){0.f, 0.f, 0.f, 0.f};

  const int kt0 = split * 16;
  for (int kk = 0; kk < 16; ++kk) {
    const int kt = kt0 + kk;
    __syncthreads();
#pragma unroll
    for (int i = 0; i < 2; ++i) {
      int ch = i * 512 + t;
      int r = ch >> 2, kq = ch & 3;
      gload_lds16(Az + (size_t)r * 2048 + (kt << 5) + (kq << 3), &At[ch * 8]);
    }
#pragma unroll
    for (int i = 0; i < 2; ++i) {
      int ch = i * 512 + t;
      int r = ch >> 2, kq = ch & 3;
      gload_lds16(Bz + (size_t)r * 2048 + (kt << 5) + (kq << 3), &Bt[ch * 8]);
    }
    __syncthreads();
    bf16x8 af[8], bq[4];
#pragma unroll
    for (int m = 0; m < 8; ++m)
      af[m] = *(const bf16x8*)&At[(wrow0 + m * 16 + l16) * 32 + lq * 8];
#pragma unroll
    for (int n = 0; n < 4; ++n)
      bq[n] = *(const bf16x8*)&Bt[(wcol0 + n * 16 + l16) * 32 + lq * 8];
#pragma unroll
    for (int m = 0; m < 8; ++m)
#pragma unroll
      for (int n = 0; n < 4; ++n)
        acc[m][n] = __builtin_amdgcn_mfma_f32_16x16x32_bf16(af[m], bq[n], acc[m][n], 0, 0, 0);
  }
  float* out = amatf + (size_t)b * 256 * 256;
#pragma unroll
  for (int m = 0; m < 8; ++m)
#pragma unroll
    for (int n = 0; n < 4; ++n)
#pragma unroll
      for (int r = 0; r < 4; ++r) {
        int gr = wrow0 + m * 16 + lq * 4 + r;
        int gc = wcol0 + n * 16 + l16;
        unsafeAtomicAdd(&out[gr * 256 + gc], acc[m][n][r]);
      }
}

// ---- G4: mmat[b][co,c'] = (1/N) sum_ch ww[co,ch] amatf[b][c',ch]; B reg-staged f32->bf16 ----
__global__ __launch_bounds__(256) void k_gemm_f32b(const unsigned short* __restrict__ ww,
                                                   const float* __restrict__ amatf,
                                                   unsigned short* __restrict__ mmat) {
  __shared__ __align__(16) __bf16 At[64 * 32];
  __shared__ __align__(16) __bf16 Bt[64 * 32];
  const int t = threadIdx.x;
  const int lid = blockIdx.x;              // 512 blocks
  const int b = (lid & 7) + 8 * ((lid >> 3) / 32);
  const int tt = (lid >> 3) % 32;
  const int col0 = (tt & 3) * 64;          // c'
  const int row0 = (tt >> 2) * 64;         // co
  const float* Bz = amatf + (size_t)b * 256 * 256;
  const int w = t >> 6, lane = t & 63;
  const int l16 = lane & 15, lq = lane >> 4;
  const int wrow0 = (w >> 1) * 32, wcol0 = (w & 1) * 32;

  floatx4 acc[2][2];
#pragma unroll
  for (int m = 0; m < 2; ++m)
#pragma unroll
    for (int n = 0; n < 2; ++n) acc[m][n] = (floatx4){0.f, 0.f, 0.f, 0.f};

  for (int kt = 0; kt < 8; ++kt) {
    __syncthreads();
    { // A: ww bf16, 256 chunks = 1/thread
      int r = t >> 2, kq = t & 3;
      gload_lds16(ww + (size_t)(row0 + r) * 256 + (kt << 5) + (kq << 3), &At[t * 8]);
    }
    { // B: amatf f32 -> bf16, 1 chunk of 8/thread
      int r = t >> 2, kq = t & 3;
      const float* src = Bz + (size_t)(col0 + r) * 256 + (kt << 5) + (kq << 3);
      float4 a = *(const float4*)src;
      float4 c = *(const float4*)(src + 4);
      union { unsigned short s[8]; bf16x8 v; } pk;
      pk.s[0] = f2bf(a.x); pk.s[1] = f2bf(a.y); pk.s[2] = f2bf(a.z); pk.s[3] = f2bf(a.w);
      pk.s[4] = f2bf(c.x); pk.s[5] = f2bf(c.y); pk.s[6] = f2bf(c.z); pk.s[7] = f2bf(c.w);
      *(bf16x8*)&Bt[t * 8] = pk.v;
    }
    __syncthreads();
    bf16x8 af[2], bq[2];
#pragma unroll
    for (int m = 0; m < 2; ++m)
      af[m] = *(const bf16x8*)&At[(wrow0 + m * 16 + l16) * 32 + lq * 8];
#pragma unroll
    for (int n = 0; n < 2; ++n)
      bq[n] = *(const bf16x8*)&Bt[(wcol0 + n * 16 + l16) * 32 + lq * 8];
#pragma unroll
    for (int m = 0; m < 2; ++m)
#pragma unroll
      for (int n = 0; n < 2; ++n)
        acc[m][n] = __builtin_amdgcn_mfma_f32_16x16x32_bf16(af[m], bq[n], acc[m][n], 0, 0, 0);
  }
  unsigned short* Cz = mmat + (size_t)b * 512 * 256;
  const float scale = 1.f / 2048.f;
#pragma unroll
  for (int m = 0; m < 2; ++m)
#pragma unroll
    for (int n = 0; n < 2; ++n)
#pragma unroll
      for (int r = 0; r < 4; ++r) {
        int gr = row0 + wrow0 + m * 16 + lq * 4 + r;
        int gc = col0 + wcol0 + n * 16 + l16;
        Cz[(size_t)gr * 256 + gc] = f2bf(acc[m][n][r] * scale);
      }
}

// ---- finalize: compute scale/shift from bnsum, out = w*sc + sh + x ----
__global__ __launch_bounds__(256) void k_final(const unsigned short* __restrict__ w,
                                               const float* __restrict__ x,
                                               const float* __restrict__ bnsum,
                                               const float* __restrict__ gamma,
                                               const float* __restrict__ beta,
                                               float* __restrict__ out) {
  __shared__ float ssc[512], ssh[512];
  const int t = threadIdx.x;
#pragma unroll
  for (int i = 0; i < 2; ++i) {
    int c = t + i * 256;
    float S = bnsum[c], SS = bnsum[512 + c];
    const float inv = 1.f / 32768.f;
    float mean = S * inv;
    float var = SS * inv - mean * mean;
    float rs = rsqrtf(var + 1e-5f);
    float sc = gamma[c] * rs;
    ssc[c] = sc;
    ssh[c] = beta[c] - mean * sc;
  }
  __syncthreads();
  const size_t total4 = (size_t)16 * 512 * 2048 / 4;
  size_t stride = (size_t)gridDim.x * 256;
  for (size_t i = (size_t)blockIdx.x * 256 + t; i < total4; i += stride) {
    size_t e = i * 4;
    int c = (int)((e >> 11) & 511);
    float sc = ssc[c], sh = ssh[c];
    uint2 wv = *(const uint2*)(w + e);
    float4 xv = *(const float4*)(x + e);
    float4 o;
    union { unsigned q; float f; } a;
    a.q = wv.x << 16;          o.x = a.f * sc + sh + xv.x;
    a.q = wv.x & 0xFFFF0000u;  o.y = a.f * sc + sh + xv.y;
    a.q = wv.y << 16;          o.z = a.f * sc + sh + xv.z;
    a.q = wv.y & 0xFFFF0000u;  o.w = a.f * sc + sh + xv.w;
    *(float4*)(out + e) = o;
  }
}

extern "C" void kernel_launch(void* const* d_in, const int* in_sizes, int n_in,
                              void* d_out, int out_size, void* d_ws, size_t ws_size,
                              hipStream_t stream) {
  const float* x       = (const float*)d_in[0];
  const float* theta_w = (const float*)d_in[1];
  const float* theta_b = (const float*)d_in[2];
  const float* phi_w   = (const float*)d_in[3];
  const float* phi_b   = (const float*)d_in[4];
  const float* g_w     = (const float*)d_in[5];
  const float* g_b     = (const float*)d_in[6];
  const float* W_w     = (const float*)d_in[7];
  const float* W_b     = (const float*)d_in[8];
  const float* gamma   = (const float*)d_in[9];
  const float* beta    = (const float*)d_in[10];
  float* out = (float*)d_out;

  char* ws = (char*)d_ws;
  size_t off = 0;
  auto alloc = [&](size_t bytes) {
    char* p = ws + off;
    off = (off + bytes + 255) & ~(size_t)255;
    return p;
  };
  unsigned short* xt    = (unsigned short*)alloc((size_t)16 * 2048 * 512 * 2);
  unsigned short* phg   = (unsigned short*)alloc((size_t)16 * 512 * 2048 * 2);
  unsigned short* tht   = (unsigned short*)alloc((size_t)16 * 2048 * 256 * 2);
  float*          amatf = (float*)alloc((size_t)16 * 256 * 256 * 4);
  float*          bnsum = (float*)alloc(1024 * 4);                  // contiguous after amatf
  unsigned short* mmat  = (unsigned short*)alloc((size_t)16 * 512 * 256 * 2);
  unsigned short* wbuf  = (unsigned short*)alloc((size_t)16 * 512 * 2048 * 2);
  unsigned short* wpg   = (unsigned short*)alloc((size_t)512 * 512 * 2);
  unsigned short* thw   = (unsigned short*)alloc((size_t)256 * 512 * 2);
  unsigned short* ww    = (unsigned short*)alloc((size_t)512 * 256 * 2);
  float* pgbias         = (float*)alloc(512 * 4);
  (void)ws_size; (void)in_sizes; (void)n_in; (void)out_size;

  const size_t sXT = (size_t)2048 * 512;
  const size_t sPG = (size_t)512 * 2048;
  const size_t sTH = (size_t)2048 * 256;
  const size_t sMM = (size_t)512 * 256;
  const size_t sW  = (size_t)512 * 2048;

  // zero atomic accumulators (amatf + bnsum are contiguous)
  hipMemsetAsync(amatf, 0, (size_t)16 * 256 * 256 * 4 + 1024 * 4, stream);

  k_transpose<<<dim3(32, 8, 17), 256, 0, stream>>>(x, xt, phi_w, g_w, theta_w, W_w,
                                                   phi_b, g_b, wpg, thw, ww, pgbias);

  // G1: PhG[o,n] = sum_c Wpg[o,c] xt[n,c] + pgbias[o]   (M=512,N=2048,K=512)
  k_gemm<128, 128, 1, false, 64, 16><<<1024, 256, 0, stream>>>(
      wpg, xt, phg, 2048, 512, 0, sXT, sPG, pgbias, 1.f, nullptr);
  // G2: tht[n,o] = sum_c xt[n,c] thw[o,c] + theta_b[o]  (M=2048,N=256,K=512)
  k_gemm<128, 128, 2, false, 32, 2><<<512, 256, 0, stream>>>(
      xt, thw, tht, 256, 512, sXT, 0, sTH, theta_b, 1.f, nullptr);
  // G3: amatf[c',c] += sum_n ph[c',n] g[c,n]  (split-K, atomic f32)
  k_gemm_splitk<<<64, 512, 0, stream>>>(phg, amatf);
  // G4: mmat[co,c'] = (1/N) sum_ch ww[co,ch] amatf[c',ch]
  k_gemm_f32b<<<512, 256, 0, stream>>>(ww, amatf, mmat);
  // G5: w[co,n] = sum_c' mmat[co,c'] tht[n,c'] + W_b[co], with BN sums
  k_gemm<128, 128, 1, true, 64, 16><<<1024, 256, 0, stream>>>(
      mmat, tht, wbuf, 2048, 256, sMM, sTH, sW, W_b, 1.f, bnsum);

  k_final<<<4096, 256, 0, stream>>>(wbuf, x, bnsum, gamma, beta, out);
}

// Round 3
// 290.839 us; speedup vs baseline: 1.1192x; 1.1192x over previous
//
#include <hip/hip_runtime.h>

typedef __bf16 bf16x8 __attribute__((ext_vector_type(8)));
typedef float floatx4 __attribute__((ext_vector_type(4)));

#define DEVI __device__ __forceinline__

DEVI unsigned short f2bf(float f) {
  union { float f; unsigned u; } v; v.f = f;
  unsigned r = v.u + 0x7FFFu + ((v.u >> 16) & 1u);
  return (unsigned short)(r >> 16);
}

DEVI void gload_lds16(const void* g, void* l) {
  __builtin_amdgcn_global_load_lds((const __attribute__((address_space(1))) void*)g,
                                   (__attribute__((address_space(3))) void*)l,
                                   16, 0, 0);
}

// ---- transpose-convert x[B,512,2048] f32 -> xt[B,2048,512] bf16 ; z==16 slice does weight prep ----
__global__ __launch_bounds__(256) void k_transpose(
    const float* __restrict__ x, unsigned short* __restrict__ xt,
    const float* __restrict__ phi_w, const float* __restrict__ g_w,
    const float* __restrict__ theta_w, const float* __restrict__ W_w,
    const float* __restrict__ phi_b, const float* __restrict__ g_b,
    unsigned short* __restrict__ wpg, unsigned short* __restrict__ thw,
    unsigned short* __restrict__ ww, float* __restrict__ pgbias) {
  const int t = threadIdx.x;
  if (blockIdx.z == 16) {
    const int T0 = 512 * 512, T1 = T0 + 256 * 512, T2 = T1 + 512 * 256, T3 = T2 + 512;
    int base = (blockIdx.y * 32 + blockIdx.x) * 256 + t;
    for (int i = base; i < T3; i += 65536) {
      if (i < T0) {
        int o = i >> 9, c = i & 511;
        float v = (o < 256) ? phi_w[o * 512 + c] : g_w[(o - 256) * 512 + c];
        wpg[i] = f2bf(v);
      } else if (i < T1) {
        int j = i - T0; thw[j] = f2bf(theta_w[j]);
      } else if (i < T2) {
        int j = i - T1; ww[j] = f2bf(W_w[j]);
      } else {
        int o = i - T2; pgbias[o] = (o < 256) ? phi_b[o] : g_b[o - 256];
      }
    }
    return;
  }
  __shared__ float tile[64][65];
  const int b = blockIdx.z, c0 = blockIdx.y * 64, n0 = blockIdx.x * 64;
  const float* xb = x + (size_t)b * 512 * 2048;
#pragma unroll
  for (int i = 0; i < 16; ++i) {
    int lin = i * 256 + t;
    int lc = lin >> 6, ln = lin & 63;
    tile[lc][ln] = xb[(size_t)(c0 + lc) * 2048 + (n0 + ln)];
  }
  __syncthreads();
  unsigned short* xtb = xt + (size_t)b * 2048 * 512;
#pragma unroll
  for (int i = 0; i < 16; ++i) {
    int lin = i * 256 + t;
    int ln = lin >> 6, lc = lin & 63;
    xtb[(size_t)(n0 + ln) * 512 + (c0 + lc)] = f2bf(tile[lc][ln]);
  }
}

// ---- GEMM C[i,j] = scale*sum_k A[i,k]B[j,k] (+bias); BK=64, XOR-swizzled LDS, 4 waves ----
// LDS layout: element (r, ke) at byte r*128 + (ke*2 ^ ((r&7)<<4)). Stage with pre-swizzled
// global source (linear gload_lds dest); read with same XOR on the ds address (rule 21).
// EPI: 0 none, 1 +bias[row], 2 +bias[col]. grid: (colTiles, rowTiles, 16 batches).
template <int BM, int BN, int EPI>
__global__ __launch_bounds__(256) void k_gemm(
    const unsigned short* __restrict__ A, const unsigned short* __restrict__ B,
    unsigned short* __restrict__ C, int N, int K,
    size_t sA, size_t sB, size_t sC,
    const float* __restrict__ bias, float scale) {
  constexpr int WM = BM / 2, WN = BN / 2;
  constexpr int FM = WM / 16, FN = WN / 16;
  __shared__ __align__(16) __bf16 At[BM * 64];
  __shared__ __align__(16) __bf16 Bt[BN * 64];
  const int t = threadIdx.x;
  const int z = blockIdx.z;
  const int row0 = blockIdx.y * BM, col0 = blockIdx.x * BN;
  const unsigned short* Az = A + (size_t)z * sA;
  const unsigned short* Bz = B + (size_t)z * sB;
  unsigned short* Cz = C + (size_t)z * sC;

  const int w = t >> 6, lane = t & 63;
  const int l16 = lane & 15, lq = lane >> 4;
  const int wrow0 = (w >> 1) * WM, wcol0 = (w & 1) * WN;
  const int xorb = (l16 & 7) << 4;
  const int aoff0 = (wrow0 + l16) * 128;   // byte base of A-fragment rows
  const int boff0 = (wcol0 + l16) * 128;

  floatx4 acc[FM][FN];
#pragma unroll
  for (int m = 0; m < FM; ++m)
#pragma unroll
    for (int n = 0; n < FN; ++n) acc[m][n] = (floatx4){0.f, 0.f, 0.f, 0.f};

  const int kt_end = K >> 6;
  for (int kt = 0; kt < kt_end; ++kt) {
    __syncthreads();
#pragma unroll
    for (int i = 0; i < BM * 8 / 256; ++i) {
      int ch = i * 256 + t;
      int r = ch >> 3;
      int sc = ((((ch & 7) << 4) ^ ((r & 7) << 4)) >> 1);  // swizzled source element
      gload_lds16(Az + (size_t)(row0 + r) * K + (kt << 6) + sc, &At[ch * 8]);
    }
#pragma unroll
    for (int i = 0; i < BN * 8 / 256; ++i) {
      int ch = i * 256 + t;
      int r = ch >> 3;
      int sc = ((((ch & 7) << 4) ^ ((r & 7) << 4)) >> 1);
      gload_lds16(Bz + (size_t)(col0 + r) * K + (kt << 6) + sc, &Bt[ch * 8]);
    }
    __syncthreads();

#pragma unroll
    for (int kk = 0; kk < 2; ++kk) {
      const int ck = ((kk << 6) + (lq << 4)) ^ xorb;
      bf16x8 af[FM], bq[FN];
#pragma unroll
      for (int m = 0; m < FM; ++m)
        af[m] = *(const bf16x8*)((const char*)At + aoff0 + m * 2048 + ck);
#pragma unroll
      for (int n = 0; n < FN; ++n)
        bq[n] = *(const bf16x8*)((const char*)Bt + boff0 + n * 2048 + ck);
#pragma unroll
      for (int m = 0; m < FM; ++m)
#pragma unroll
        for (int n = 0; n < FN; ++n)
          acc[m][n] = __builtin_amdgcn_mfma_f32_16x16x32_bf16(af[m], bq[n], acc[m][n], 0, 0, 0);
    }
  }

#pragma unroll
  for (int m = 0; m < FM; ++m)
#pragma unroll
    for (int n = 0; n < FN; ++n) {
      int gc = col0 + wcol0 + n * 16 + l16;
      float bc = (EPI == 2) ? bias[gc] : 0.f;
#pragma unroll
      for (int r = 0; r < 4; ++r) {
        int gr = row0 + wrow0 + m * 16 + lq * 4 + r;
        float v = acc[m][n][r] * scale;
        if (EPI == 1) v += bias[gr];
        if (EPI == 2) v += bc;
        Cz[(size_t)gr * N + gc] = f2bf(v);
      }
    }
}

// ---- G3: amatf[b][c',c] += split-K partial of sum_n ph[c',n] g[c,n] ----
// grid (16 splits, 1, 16 batches) = 256 blocks x 8 waves; 2 BK-64 steps each.
__global__ __launch_bounds__(512) void k_gemm_splitk(const unsigned short* __restrict__ phg,
                                                     float* __restrict__ amatf) {
  __shared__ __align__(16) __bf16 At[256 * 64];
  __shared__ __align__(16) __bf16 Bt[256 * 64];
  const int t = threadIdx.x;
  const int split = blockIdx.x, b = blockIdx.z;
  const size_t sPG = (size_t)512 * 2048;
  const unsigned short* Az = phg + (size_t)b * sPG;       // ph rows
  const unsigned short* Bz = Az + (size_t)256 * 2048;     // g rows
  const int w = t >> 6, lane = t & 63;
  const int l16 = lane & 15, lq = lane >> 4;
  const int wrow0 = (w >> 2) * 128, wcol0 = (w & 3) * 64;
  const int xorb = (l16 & 7) << 4;
  const int aoff0 = (wrow0 + l16) * 128;
  const int boff0 = (wcol0 + l16) * 128;

  floatx4 acc[8][4];
#pragma unroll
  for (int m = 0; m < 8; ++m)
#pragma unroll
    for (int n = 0; n < 4; ++n) acc[m][n] = (floatx4){0.f, 0.f, 0.f, 0.f};

#pragma unroll
  for (int ks = 0; ks < 2; ++ks) {
    const int kt = split * 2 + ks;
    __syncthreads();
#pragma unroll
    for (int i = 0; i < 4; ++i) {
      int ch = i * 512 + t;
      int r = ch >> 3;
      int sc = ((((ch & 7) << 4) ^ ((r & 7) << 4)) >> 1);
      gload_lds16(Az + (size_t)r * 2048 + (kt << 6) + sc, &At[ch * 8]);
    }
#pragma unroll
    for (int i = 0; i < 4; ++i) {
      int ch = i * 512 + t;
      int r = ch >> 3;
      int sc = ((((ch & 7) << 4) ^ ((r & 7) << 4)) >> 1);
      gload_lds16(Bz + (size_t)r * 2048 + (kt << 6) + sc, &Bt[ch * 8]);
    }
    __syncthreads();
#pragma unroll
    for (int kk = 0; kk < 2; ++kk) {
      const int ck = ((kk << 6) + (lq << 4)) ^ xorb;
      bf16x8 af[8], bq[4];
#pragma unroll
      for (int m = 0; m < 8; ++m)
        af[m] = *(const bf16x8*)((const char*)At + aoff0 + m * 2048 + ck);
#pragma unroll
      for (int n = 0; n < 4; ++n)
        bq[n] = *(const bf16x8*)((const char*)Bt + boff0 + n * 2048 + ck);
#pragma unroll
      for (int m = 0; m < 8; ++m)
#pragma unroll
        for (int n = 0; n < 4; ++n)
          acc[m][n] = __builtin_amdgcn_mfma_f32_16x16x32_bf16(af[m], bq[n], acc[m][n], 0, 0, 0);
    }
  }
  float* out = amatf + (size_t)b * 256 * 256;
#pragma unroll
  for (int m = 0; m < 8; ++m)
#pragma unroll
    for (int n = 0; n < 4; ++n)
#pragma unroll
      for (int r = 0; r < 4; ++r) {
        int gr = wrow0 + m * 16 + lq * 4 + r;
        int gc = wcol0 + n * 16 + l16;
        unsafeAtomicAdd(&out[gr * 256 + gc], acc[m][n][r]);
      }
}

// ---- G4: mmat[b][co,c'] = (1/N) sum_ch ww[co,ch] amatf[b][c',ch]; B reg-staged f32->bf16 ----
__global__ __launch_bounds__(256) void k_gemm_f32b(const unsigned short* __restrict__ ww,
                                                   const float* __restrict__ amatf,
                                                   unsigned short* __restrict__ mmat) {
  __shared__ __align__(16) __bf16 At[64 * 32];
  __shared__ __align__(16) __bf16 Bt[64 * 32];
  const int t = threadIdx.x;
  const int b = blockIdx.z;
  const int col0 = blockIdx.x * 64;   // c'
  const int row0 = blockIdx.y * 64;   // co
  const float* Bz = amatf + (size_t)b * 256 * 256;
  const int w = t >> 6, lane = t & 63;
  const int l16 = lane & 15, lq = lane >> 4;
  const int wrow0 = (w >> 1) * 32, wcol0 = (w & 1) * 32;

  floatx4 acc[2][2];
#pragma unroll
  for (int m = 0; m < 2; ++m)
#pragma unroll
    for (int n = 0; n < 2; ++n) acc[m][n] = (floatx4){0.f, 0.f, 0.f, 0.f};

  for (int kt = 0; kt < 8; ++kt) {
    __syncthreads();
    {
      int r = t >> 2, kq = t & 3;
      gload_lds16(ww + (size_t)(row0 + r) * 256 + (kt << 5) + (kq << 3), &At[t * 8]);
    }
    {
      int r = t >> 2, kq = t & 3;
      const float* src = Bz + (size_t)(col0 + r) * 256 + (kt << 5) + (kq << 3);
      float4 a = *(const float4*)src;
      float4 c = *(const float4*)(src + 4);
      union { unsigned short s[8]; bf16x8 v; } pk;
      pk.s[0] = f2bf(a.x); pk.s[1] = f2bf(a.y); pk.s[2] = f2bf(a.z); pk.s[3] = f2bf(a.w);
      pk.s[4] = f2bf(c.x); pk.s[5] = f2bf(c.y); pk.s[6] = f2bf(c.z); pk.s[7] = f2bf(c.w);
      *(bf16x8*)&Bt[t * 8] = pk.v;
    }
    __syncthreads();
    bf16x8 af[2], bq[2];
#pragma unroll
    for (int m = 0; m < 2; ++m)
      af[m] = *(const bf16x8*)&At[(wrow0 + m * 16 + l16) * 32 + lq * 8];
#pragma unroll
    for (int n = 0; n < 2; ++n)
      bq[n] = *(const bf16x8*)&Bt[(wcol0 + n * 16 + l16) * 32 + lq * 8];
#pragma unroll
    for (int m = 0; m < 2; ++m)
#pragma unroll
      for (int n = 0; n < 2; ++n)
        acc[m][n] = __builtin_amdgcn_mfma_f32_16x16x32_bf16(af[m], bq[n], acc[m][n], 0, 0, 0);
  }
  unsigned short* Cz = mmat + (size_t)b * 512 * 256;
  const float scale = 1.f / 2048.f;
#pragma unroll
  for (int m = 0; m < 2; ++m)
#pragma unroll
    for (int n = 0; n < 2; ++n)
#pragma unroll
      for (int r = 0; r < 4; ++r) {
        int gr = row0 + wrow0 + m * 16 + lq * 4 + r;
        int gc = col0 + wcol0 + n * 16 + l16;
        Cz[(size_t)gr * 256 + gc] = f2bf(acc[m][n][r] * scale);
      }
}

// ---- BN stats: per channel c, mean/var over (B,N); emit scale/shift ----
__global__ __launch_bounds__(256) void k_bnstats(const unsigned short* __restrict__ w,
                                                 const float* __restrict__ gamma,
                                                 const float* __restrict__ beta,
                                                 float* __restrict__ scale,
                                                 float* __restrict__ shift) {
  const int c = blockIdx.x, t = threadIdx.x;
  float s = 0.f, ss = 0.f;
  for (int b = 0; b < 16; ++b) {
    const unsigned short* p = w + ((size_t)b * 512 + c) * 2048 + t * 8;
    uint4 v = *(const uint4*)p;
    unsigned u[4] = {v.x, v.y, v.z, v.w};
#pragma unroll
    for (int j = 0; j < 4; ++j) {
      union { unsigned q; float f; } a, bb;
      a.q = u[j] << 16;
      bb.q = u[j] & 0xFFFF0000u;
      s += a.f + bb.f;
      ss += a.f * a.f + bb.f * bb.f;
    }
  }
#pragma unroll
  for (int off = 32; off; off >>= 1) {
    s += __shfl_down(s, off);
    ss += __shfl_down(ss, off);
  }
  __shared__ float ls[4], lss[4];
  if ((t & 63) == 0) { ls[t >> 6] = s; lss[t >> 6] = ss; }
  __syncthreads();
  if (t == 0) {
    float S = ls[0] + ls[1] + ls[2] + ls[3];
    float SS = lss[0] + lss[1] + lss[2] + lss[3];
    const float inv = 1.f / 32768.f;
    float mean = S * inv;
    float var = SS * inv - mean * mean;
    float rs = rsqrtf(var + 1e-5f);
    float sc = gamma[c] * rs;
    scale[c] = sc;
    shift[c] = beta[c] - mean * sc;
  }
}

// ---- finalize: out = w*scale[c] + shift[c] + x ----
__global__ __launch_bounds__(256) void k_final(const unsigned short* __restrict__ w,
                                               const float* __restrict__ x,
                                               const float* __restrict__ scale,
                                               const float* __restrict__ shift,
                                               float* __restrict__ out) {
  const size_t total4 = (size_t)16 * 512 * 2048 / 4;
  size_t stride = (size_t)gridDim.x * 256;
  for (size_t i = (size_t)blockIdx.x * 256 + threadIdx.x; i < total4; i += stride) {
    size_t e = i * 4;
    int c = (int)((e >> 11) & 511);
    float sc = scale[c], sh = shift[c];
    uint2 wv = *(const uint2*)(w + e);
    float4 xv = *(const float4*)(x + e);
    float4 o;
    union { unsigned q; float f; } a;
    a.q = wv.x << 16;          o.x = a.f * sc + sh + xv.x;
    a.q = wv.x & 0xFFFF0000u;  o.y = a.f * sc + sh + xv.y;
    a.q = wv.y << 16;          o.z = a.f * sc + sh + xv.z;
    a.q = wv.y & 0xFFFF0000u;  o.w = a.f * sc + sh + xv.w;
    *(float4*)(out + e) = o;
  }
}

extern "C" void kernel_launch(void* const* d_in, const int* in_sizes, int n_in,
                              void* d_out, int out_size, void* d_ws, size_t ws_size,
                              hipStream_t stream) {
  const float* x       = (const float*)d_in[0];
  const float* theta_w = (const float*)d_in[1];
  const float* theta_b = (const float*)d_in[2];
  const float* phi_w   = (const float*)d_in[3];
  const float* phi_b   = (const float*)d_in[4];
  const float* g_w     = (const float*)d_in[5];
  const float* g_b     = (const float*)d_in[6];
  const float* W_w     = (const float*)d_in[7];
  const float* W_b     = (const float*)d_in[8];
  const float* gamma   = (const float*)d_in[9];
  const float* beta    = (const float*)d_in[10];
  float* out = (float*)d_out;

  char* ws = (char*)d_ws;
  size_t off = 0;
  auto alloc = [&](size_t bytes) {
    char* p = ws + off;
    off = (off + bytes + 255) & ~(size_t)255;
    return p;
  };
  unsigned short* xt    = (unsigned short*)alloc((size_t)16 * 2048 * 512 * 2);
  unsigned short* phg   = (unsigned short*)alloc((size_t)16 * 512 * 2048 * 2);
  unsigned short* tht   = (unsigned short*)alloc((size_t)16 * 2048 * 256 * 2);
  float*          amatf = (float*)alloc((size_t)16 * 256 * 256 * 4);
  unsigned short* mmat  = (unsigned short*)alloc((size_t)16 * 512 * 256 * 2);
  unsigned short* wbuf  = (unsigned short*)alloc((size_t)16 * 512 * 2048 * 2);
  unsigned short* wpg   = (unsigned short*)alloc((size_t)512 * 512 * 2);
  unsigned short* thw   = (unsigned short*)alloc((size_t)256 * 512 * 2);
  unsigned short* ww    = (unsigned short*)alloc((size_t)512 * 256 * 2);
  float* pgbias         = (float*)alloc(512 * 4);
  float* scalev         = (float*)alloc(512 * 4);
  float* shiftv         = (float*)alloc(512 * 4);
  (void)ws_size; (void)in_sizes; (void)n_in; (void)out_size;

  const size_t sXT = (size_t)2048 * 512;
  const size_t sPG = (size_t)512 * 2048;
  const size_t sTH = (size_t)2048 * 256;
  const size_t sMM = (size_t)512 * 256;
  const size_t sW  = (size_t)512 * 2048;

  hipMemsetAsync(amatf, 0, (size_t)16 * 256 * 256 * 4, stream);

  k_transpose<<<dim3(32, 8, 17), 256, 0, stream>>>(x, xt, phi_w, g_w, theta_w, W_w,
                                                   phi_b, g_b, wpg, thw, ww, pgbias);

  // G1: PhG[o,n] = sum_c Wpg[o,c] xt[n,c] + pgbias[o]   (M=512,N=2048,K=512)
  k_gemm<128, 128, 1><<<dim3(16, 4, 16), 256, 0, stream>>>(
      wpg, xt, phg, 2048, 512, 0, sXT, sPG, pgbias, 1.f);
  // G2: tht[n,o] = sum_c xt[n,c] thw[o,c] + theta_b[o]  (M=2048,N=256,K=512)
  k_gemm<128, 128, 2><<<dim3(2, 16, 16), 256, 0, stream>>>(
      xt, thw, tht, 256, 512, sXT, 0, sTH, theta_b, 1.f);
  // G3: amatf[c',c] += sum_n ph[c',n] g[c,n]  (split-K 16, atomic f32)
  k_gemm_splitk<<<dim3(16, 1, 16), 512, 0, stream>>>(phg, amatf);
  // G4: mmat[co,c'] = (1/N) sum_ch ww[co,ch] amatf[c',ch]
  k_gemm_f32b<<<dim3(4, 8, 16), 256, 0, stream>>>(ww, amatf, mmat);
  // G5: w[co,n] = sum_c' mmat[co,c'] tht[n,c'] + W_b[co]  (M=512,N=2048,K=256)
  k_gemm<128, 128, 1><<<dim3(16, 4, 16), 256, 0, stream>>>(
      mmat, tht, wbuf, 2048, 256, sMM, sTH, sW, W_b, 1.f);

  k_bnstats<<<512, 256, 0, stream>>>(wbuf, gamma, beta, scalev, shiftv);
  k_final<<<4096, 256, 0, stream>>>(wbuf, x, scalev, shiftv, out);
}

// Round 5
// 253.054 us; speedup vs baseline: 1.2864x; 1.1493x over previous
//
#include <hip/hip_runtime.h>

typedef __bf16 bf16x8 __attribute__((ext_vector_type(8)));
typedef float floatx4 __attribute__((ext_vector_type(4)));

#define DEVI __device__ __forceinline__

DEVI unsigned short f2bf(float f) {
  union { float f; unsigned u; } v; v.f = f;
  unsigned r = v.u + 0x7FFFu + ((v.u >> 16) & 1u);
  return (unsigned short)(r >> 16);
}

DEVI void gload_lds16(const void* g, void* l) {
  __builtin_amdgcn_global_load_lds((const __attribute__((address_space(1))) void*)g,
                                   (__attribute__((address_space(3))) void*)l,
                                   16, 0, 0);
}

// ---- transpose-convert x[B,512,2048] f32 -> xt[B,2048,512] bf16 ; z==16 slice does weight prep ----
__global__ __launch_bounds__(256) void k_transpose(
    const float* __restrict__ x, unsigned short* __restrict__ xt,
    const float* __restrict__ phi_w, const float* __restrict__ g_w,
    const float* __restrict__ theta_w, const float* __restrict__ W_w,
    const float* __restrict__ phi_b, const float* __restrict__ g_b,
    unsigned short* __restrict__ wpg, unsigned short* __restrict__ thw,
    unsigned short* __restrict__ ww, float* __restrict__ pgbias) {
  const int t = threadIdx.x;
  if (blockIdx.z == 16) {
    const int T0 = 512 * 512, T1 = T0 + 256 * 512, T2 = T1 + 512 * 256, T3 = T2 + 512;
    int base = (blockIdx.y * 32 + blockIdx.x) * 256 + t;
    for (int i = base; i < T3; i += 65536) {
      if (i < T0) {
        int o = i >> 9, c = i & 511;
        float v = (o < 256) ? phi_w[o * 512 + c] : g_w[(o - 256) * 512 + c];
        wpg[i] = f2bf(v);
      } else if (i < T1) {
        int j = i - T0; thw[j] = f2bf(theta_w[j]);
      } else if (i < T2) {
        int j = i - T1; ww[j] = f2bf(W_w[j]);
      } else {
        int o = i - T2; pgbias[o] = (o < 256) ? phi_b[o] : g_b[o - 256];
      }
    }
    return;
  }
  __shared__ float tile[64][65];
  const int b = blockIdx.z, c0 = blockIdx.y * 64, n0 = blockIdx.x * 64;
  const float* xb = x + (size_t)b * 512 * 2048;
#pragma unroll
  for (int i = 0; i < 16; ++i) {
    int lin = i * 256 + t;
    int lc = lin >> 6, ln = lin & 63;
    tile[lc][ln] = xb[(size_t)(c0 + lc) * 2048 + (n0 + ln)];
  }
  __syncthreads();
  unsigned short* xtb = xt + (size_t)b * 2048 * 512;
#pragma unroll
  for (int i = 0; i < 16; ++i) {
    int lin = i * 256 + t;
    int ln = lin >> 6, lc = lin & 63;
    xtb[(size_t)(n0 + ln) * 512 + (c0 + lc)] = f2bf(tile[lc][ln]);
  }
}

// ---- GEMM C[i,j] = scale*sum_k A[i,k]B[j,k] (+bias); BK=64, XOR-swizzled LDS, 4 waves ----
// EPI: 0 none, 1 +bias[row], 2 +bias[col]. grid: (colTiles, rowTiles, 16 batches).
template <int BM, int BN, int EPI>
__global__ __launch_bounds__(256) void k_gemm(
    const unsigned short* __restrict__ A, const unsigned short* __restrict__ B,
    unsigned short* __restrict__ C, int N, int K,
    size_t sA, size_t sB, size_t sC,
    const float* __restrict__ bias, float scale) {
  constexpr int WM = BM / 2, WN = BN / 2;
  constexpr int FM = WM / 16, FN = WN / 16;
  __shared__ __align__(16) __bf16 At[BM * 64];
  __shared__ __align__(16) __bf16 Bt[BN * 64];
  const int t = threadIdx.x;
  const int z = blockIdx.z;
  const int row0 = blockIdx.y * BM, col0 = blockIdx.x * BN;
  const unsigned short* Az = A + (size_t)z * sA;
  const unsigned short* Bz = B + (size_t)z * sB;
  unsigned short* Cz = C + (size_t)z * sC;

  const int w = t >> 6, lane = t & 63;
  const int l16 = lane & 15, lq = lane >> 4;
  const int wrow0 = (w >> 1) * WM, wcol0 = (w & 1) * WN;
  const int xorb = (l16 & 7) << 4;
  const int aoff0 = (wrow0 + l16) * 128;
  const int boff0 = (wcol0 + l16) * 128;

  floatx4 acc[FM][FN];
#pragma unroll
  for (int m = 0; m < FM; ++m)
#pragma unroll
    for (int n = 0; n < FN; ++n) acc[m][n] = (floatx4){0.f, 0.f, 0.f, 0.f};

  const int kt_end = K >> 6;
  for (int kt = 0; kt < kt_end; ++kt) {
    __syncthreads();
#pragma unroll
    for (int i = 0; i < BM * 8 / 256; ++i) {
      int ch = i * 256 + t;
      int r = ch >> 3;
      int sc = ((((ch & 7) << 4) ^ ((r & 7) << 4)) >> 1);
      gload_lds16(Az + (size_t)(row0 + r) * K + (kt << 6) + sc, &At[ch * 8]);
    }
#pragma unroll
    for (int i = 0; i < BN * 8 / 256; ++i) {
      int ch = i * 256 + t;
      int r = ch >> 3;
      int sc = ((((ch & 7) << 4) ^ ((r & 7) << 4)) >> 1);
      gload_lds16(Bz + (size_t)(col0 + r) * K + (kt << 6) + sc, &Bt[ch * 8]);
    }
    __syncthreads();

#pragma unroll
    for (int kk = 0; kk < 2; ++kk) {
      const int ck = ((kk << 6) + (lq << 4)) ^ xorb;
      bf16x8 af[FM], bq[FN];
#pragma unroll
      for (int m = 0; m < FM; ++m)
        af[m] = *(const bf16x8*)((const char*)At + aoff0 + m * 2048 + ck);
#pragma unroll
      for (int n = 0; n < FN; ++n)
        bq[n] = *(const bf16x8*)((const char*)Bt + boff0 + n * 2048 + ck);
#pragma unroll
      for (int m = 0; m < FM; ++m)
#pragma unroll
        for (int n = 0; n < FN; ++n)
          acc[m][n] = __builtin_amdgcn_mfma_f32_16x16x32_bf16(af[m], bq[n], acc[m][n], 0, 0, 0);
    }
  }

#pragma unroll
  for (int m = 0; m < FM; ++m)
#pragma unroll
    for (int n = 0; n < FN; ++n) {
      int gc = col0 + wcol0 + n * 16 + l16;
      float bc = (EPI == 2) ? bias[gc] : 0.f;
#pragma unroll
      for (int r = 0; r < 4; ++r) {
        int gr = row0 + wrow0 + m * 16 + lq * 4 + r;
        float v = acc[m][n][r] * scale;
        if (EPI == 1) v += bias[gr];
        if (EPI == 2) v += bc;
        Cz[(size_t)gr * N + gc] = f2bf(v);
      }
    }
}

// ---- G3: pbuf[s][b][c'][c] = partial_{K-slice s} sum_n ph[c',n] g[c,n]  (NO atomics) ----
// grid (16, 1, 16): x decodes (split 2b | tr 1b | tc 1b); 128x128 tile, 4 waves, 8 BK-64 steps.
__global__ __launch_bounds__(256) void k_gemm_part(const unsigned short* __restrict__ phg,
                                                   float* __restrict__ pbuf) {
  __shared__ __align__(16) __bf16 At[128 * 64];
  __shared__ __align__(16) __bf16 Bt[128 * 64];
  const int t = threadIdx.x;
  const int tid = blockIdx.x, b = blockIdx.z;
  const int split = tid >> 2, tr = (tid >> 1) & 1, tc = tid & 1;
  const int row0 = tr * 128, col0 = tc * 128;
  const size_t sPG = (size_t)512 * 2048;
  const unsigned short* Az = phg + (size_t)b * sPG + (size_t)row0 * 2048;          // ph rows
  const unsigned short* Bz = phg + (size_t)b * sPG + (size_t)(256 + col0) * 2048;  // g rows
  const int w = t >> 6, lane = t & 63;
  const int l16 = lane & 15, lq = lane >> 4;
  const int wrow0 = (w >> 1) * 64, wcol0 = (w & 1) * 64;
  const int xorb = (l16 & 7) << 4;
  const int aoff0 = (wrow0 + l16) * 128;
  const int boff0 = (wcol0 + l16) * 128;

  floatx4 acc[4][4];
#pragma unroll
  for (int m = 0; m < 4; ++m)
#pragma unroll
    for (int n = 0; n < 4; ++n) acc[m][n] = (floatx4){0.f, 0.f, 0.f, 0.f};

  for (int kt8 = 0; kt8 < 8; ++kt8) {
    const int kt = split * 8 + kt8;
    __syncthreads();
#pragma unroll
    for (int i = 0; i < 4; ++i) {
      int ch = i * 256 + t;
      int r = ch >> 3;
      int sc = ((((ch & 7) << 4) ^ ((r & 7) << 4)) >> 1);
      gload_lds16(Az + (size_t)r * 2048 + (kt << 6) + sc, &At[ch * 8]);
    }
#pragma unroll
    for (int i = 0; i < 4; ++i) {
      int ch = i * 256 + t;
      int r = ch >> 3;
      int sc = ((((ch & 7) << 4) ^ ((r & 7) << 4)) >> 1);
      gload_lds16(Bz + (size_t)r * 2048 + (kt << 6) + sc, &Bt[ch * 8]);
    }
    __syncthreads();
#pragma unroll
    for (int kk = 0; kk < 2; ++kk) {
      const int ck = ((kk << 6) + (lq << 4)) ^ xorb;
      bf16x8 af[4], bq[4];
#pragma unroll
      for (int m = 0; m < 4; ++m)
        af[m] = *(const bf16x8*)((const char*)At + aoff0 + m * 2048 + ck);
#pragma unroll
      for (int n = 0; n < 4; ++n)
        bq[n] = *(const bf16x8*)((const char*)Bt + boff0 + n * 2048 + ck);
#pragma unroll
      for (int m = 0; m < 4; ++m)
#pragma unroll
        for (int n = 0; n < 4; ++n)
          acc[m][n] = __builtin_amdgcn_mfma_f32_16x16x32_bf16(af[m], bq[n], acc[m][n], 0, 0, 0);
    }
  }
  float* outp = pbuf + ((size_t)split * 16 + b) * 65536;  // [256][256] f32
#pragma unroll
  for (int m = 0; m < 4; ++m)
#pragma unroll
    for (int n = 0; n < 4; ++n)
#pragma unroll
      for (int r = 0; r < 4; ++r) {
        int gr = row0 + wrow0 + m * 16 + lq * 4 + r;
        int gc = col0 + wcol0 + n * 16 + l16;
        outp[(size_t)gr * 256 + gc] = acc[m][n][r];
      }
}

// ---- G4: mmat[b][co,c'] = (1/N) sum_ch ww[co,ch] (sum_s pbuf[s][b][c',ch]) ----
__global__ __launch_bounds__(256) void k_gemm_f32b(const unsigned short* __restrict__ ww,
                                                   const float* __restrict__ pbuf,
                                                   unsigned short* __restrict__ mmat) {
  __shared__ __align__(16) __bf16 At[64 * 32];
  __shared__ __align__(16) __bf16 Bt[64 * 32];
  const int t = threadIdx.x;
  const int b = blockIdx.z;
  const int col0 = blockIdx.x * 64;   // c'
  const int row0 = blockIdx.y * 64;   // co
  const size_t SSTR = (size_t)16 * 65536;
  const float* Bz = pbuf + (size_t)b * 65536;
  const int w = t >> 6, lane = t & 63;
  const int l16 = lane & 15, lq = lane >> 4;
  const int wrow0 = (w >> 1) * 32, wcol0 = (w & 1) * 32;

  floatx4 acc[2][2];
#pragma unroll
  for (int m = 0; m < 2; ++m)
#pragma unroll
    for (int n = 0; n < 2; ++n) acc[m][n] = (floatx4){0.f, 0.f, 0.f, 0.f};

  for (int kt = 0; kt < 8; ++kt) {
    __syncthreads();
    {
      int r = t >> 2, kq = t & 3;
      gload_lds16(ww + (size_t)(row0 + r) * 256 + (kt << 5) + (kq << 3), &At[t * 8]);
    }
    {
      int r = t >> 2, kq = t & 3;
      const float* src = Bz + (size_t)(col0 + r) * 256 + (kt << 5) + (kq << 3);
      float4 a = *(const float4*)src;
      float4 c = *(const float4*)(src + 4);
#pragma unroll
      for (int s = 1; s < 4; ++s) {
        float4 a2 = *(const float4*)(src + s * SSTR);
        float4 c2 = *(const float4*)(src + s * SSTR + 4);
        a.x += a2.x; a.y += a2.y; a.z += a2.z; a.w += a2.w;
        c.x += c2.x; c.y += c2.y; c.z += c2.z; c.w += c2.w;
      }
      union { unsigned short s[8]; bf16x8 v; } pk;
      pk.s[0] = f2bf(a.x); pk.s[1] = f2bf(a.y); pk.s[2] = f2bf(a.z); pk.s[3] = f2bf(a.w);
      pk.s[4] = f2bf(c.x); pk.s[5] = f2bf(c.y); pk.s[6] = f2bf(c.z); pk.s[7] = f2bf(c.w);
      *(bf16x8*)&Bt[t * 8] = pk.v;
    }
    __syncthreads();
    bf16x8 af[2], bq[2];
#pragma unroll
    for (int m = 0; m < 2; ++m)
      af[m] = *(const bf16x8*)&At[(wrow0 + m * 16 + l16) * 32 + lq * 8];
#pragma unroll
    for (int n = 0; n < 2; ++n)
      bq[n] = *(const bf16x8*)&Bt[(wcol0 + n * 16 + l16) * 32 + lq * 8];
#pragma unroll
    for (int m = 0; m < 2; ++m)
#pragma unroll
      for (int n = 0; n < 2; ++n)
        acc[m][n] = __builtin_amdgcn_mfma_f32_16x16x32_bf16(af[m], bq[n], acc[m][n], 0, 0, 0);
  }
  unsigned short* Cz = mmat + (size_t)b * 512 * 256;
  const float scale = 1.f / 2048.f;
#pragma unroll
  for (int m = 0; m < 2; ++m)
#pragma unroll
    for (int n = 0; n < 2; ++n)
#pragma unroll
      for (int r = 0; r < 4; ++r) {
        int gr = row0 + wrow0 + m * 16 + lq * 4 + r;
        int gc = col0 + wcol0 + n * 16 + l16;
        Cz[(size_t)gr * 256 + gc] = f2bf(acc[m][n][r] * scale);
      }
}

// ---- BN stats ----
__global__ __launch_bounds__(256) void k_bnstats(const unsigned short* __restrict__ w,
                                                 const float* __restrict__ gamma,
                                                 const float* __restrict__ beta,
                                                 float* __restrict__ scale,
                                                 float* __restrict__ shift) {
  const int c = blockIdx.x, t = threadIdx.x;
  float s = 0.f, ss = 0.f;
  for (int b = 0; b < 16; ++b) {
    const unsigned short* p = w + ((size_t)b * 512 + c) * 2048 + t * 8;
    uint4 v = *(const uint4*)p;
    unsigned u[4] = {v.x, v.y, v.z, v.w};
#pragma unroll
    for (int j = 0; j < 4; ++j) {
      union { unsigned q; float f; } a, bb;
      a.q = u[j] << 16;
      bb.q = u[j] & 0xFFFF0000u;
      s += a.f + bb.f;
      ss += a.f * a.f + bb.f * bb.f;
    }
  }
#pragma unroll
  for (int off = 32; off; off >>= 1) {
    s += __shfl_down(s, off);
    ss += __shfl_down(ss, off);
  }
  __shared__ float ls[4], lss[4];
  if ((t & 63) == 0) { ls[t >> 6] = s; lss[t >> 6] = ss; }
  __syncthreads();
  if (t == 0) {
    float S = ls[0] + ls[1] + ls[2] + ls[3];
    float SS = lss[0] + lss[1] + lss[2] + lss[3];
    const float inv = 1.f / 32768.f;
    float mean = S * inv;
    float var = SS * inv - mean * mean;
    float rs = rsqrtf(var + 1e-5f);
    float sc = gamma[c] * rs;
    scale[c] = sc;
    shift[c] = beta[c] - mean * sc;
  }
}

// ---- finalize: out = w*scale[c] + shift[c] + x ----
__global__ __launch_bounds__(256) void k_final(const unsigned short* __restrict__ w,
                                               const float* __restrict__ x,
                                               const float* __restrict__ scale,
                                               const float* __restrict__ shift,
                                               float* __restrict__ out) {
  const size_t total4 = (size_t)16 * 512 * 2048 / 4;
  size_t stride = (size_t)gridDim.x * 256;
  for (size_t i = (size_t)blockIdx.x * 256 + threadIdx.x; i < total4; i += stride) {
    size_t e = i * 4;
    int c = (int)((e >> 11) & 511);
    float sc = scale[c], sh = shift[c];
    uint2 wv = *(const uint2*)(w + e);
    float4 xv = *(const float4*)(x + e);
    float4 o;
    union { unsigned q; float f; } a;
    a.q = wv.x << 16;          o.x = a.f * sc + sh + xv.x;
    a.q = wv.x & 0xFFFF0000u;  o.y = a.f * sc + sh + xv.y;
    a.q = wv.y << 16;          o.z = a.f * sc + sh + xv.z;
    a.q = wv.y & 0xFFFF0000u;  o.w = a.f * sc + sh + xv.w;
    *(float4*)(out + e) = o;
  }
}

extern "C" void kernel_launch(void* const* d_in, const int* in_sizes, int n_in,
                              void* d_out, int out_size, void* d_ws, size_t ws_size,
                              hipStream_t stream) {
  const float* x       = (const float*)d_in[0];
  const float* theta_w = (const float*)d_in[1];
  const float* theta_b = (const float*)d_in[2];
  const float* phi_w   = (const float*)d_in[3];
  const float* phi_b   = (const float*)d_in[4];
  const float* g_w     = (const float*)d_in[5];
  const float* g_b     = (const float*)d_in[6];
  const float* W_w     = (const float*)d_in[7];
  const float* W_b     = (const float*)d_in[8];
  const float* gamma   = (const float*)d_in[9];
  const float* beta    = (const float*)d_in[10];
  float* out = (float*)d_out;

  char* ws = (char*)d_ws;
  size_t off = 0;
  auto alloc = [&](size_t bytes) {
    char* p = ws + off;
    off = (off + bytes + 255) & ~(size_t)255;
    return p;
  };
  unsigned short* xt    = (unsigned short*)alloc((size_t)16 * 2048 * 512 * 2);
  unsigned short* phg   = (unsigned short*)alloc((size_t)16 * 512 * 2048 * 2);
  unsigned short* tht   = (unsigned short*)alloc((size_t)16 * 2048 * 256 * 2);
  float*          pbuf  = (float*)alloc((size_t)4 * 16 * 256 * 256 * 4);   // split-K partials
  unsigned short* mmat  = (unsigned short*)alloc((size_t)16 * 512 * 256 * 2);
  unsigned short* wbuf  = (unsigned short*)alloc((size_t)16 * 512 * 2048 * 2);
  unsigned short* wpg   = (unsigned short*)alloc((size_t)512 * 512 * 2);
  unsigned short* thw   = (unsigned short*)alloc((size_t)256 * 512 * 2);
  unsigned short* ww    = (unsigned short*)alloc((size_t)512 * 256 * 2);
  float* pgbias         = (float*)alloc(512 * 4);
  float* scalev         = (float*)alloc(512 * 4);
  float* shiftv         = (float*)alloc(512 * 4);
  (void)ws_size; (void)in_sizes; (void)n_in; (void)out_size;

  const size_t sXT = (size_t)2048 * 512;
  const size_t sPG = (size_t)512 * 2048;
  const size_t sTH = (size_t)2048 * 256;
  const size_t sMM = (size_t)512 * 256;
  const size_t sW  = (size_t)512 * 2048;

  k_transpose<<<dim3(32, 8, 17), 256, 0, stream>>>(x, xt, phi_w, g_w, theta_w, W_w,
                                                   phi_b, g_b, wpg, thw, ww, pgbias);

  // G1: PhG[o,n] = sum_c Wpg[o,c] xt[n,c] + pgbias[o]   (M=512,N=2048,K=512)
  k_gemm<128, 128, 1><<<dim3(16, 4, 16), 256, 0, stream>>>(
      wpg, xt, phg, 2048, 512, 0, sXT, sPG, pgbias, 1.f);
  // G2: tht[n,o] = sum_c xt[n,c] thw[o,c] + theta_b[o]  (M=2048,N=256,K=512)
  k_gemm<128, 128, 2><<<dim3(2, 16, 16), 256, 0, stream>>>(
      xt, thw, tht, 256, 512, sXT, 0, sTH, theta_b, 1.f);
  // G3: pbuf[s][b] = K-slice partials of Ph·G^T  (no atomics)
  k_gemm_part<<<dim3(16, 1, 16), 256, 0, stream>>>(phg, pbuf);
  // G4: mmat[co,c'] = (1/N) sum_ch ww[co,ch] (sum_s pbuf[s][c',ch])
  k_gemm_f32b<<<dim3(4, 8, 16), 256, 0, stream>>>(ww, pbuf, mmat);
  // G5: w[co,n] = sum_c' mmat[co,c'] tht[n,c'] + W_b[co]  (M=512,N=2048,K=256)
  k_gemm<128, 128, 1><<<dim3(16, 4, 16), 256, 0, stream>>>(
      mmat, tht, wbuf, 2048, 256, sMM, sTH, sW, W_b, 1.f);

  k_bnstats<<<512, 256, 0, stream>>>(wbuf, gamma, beta, scalev, shiftv);
  k_final<<<4096, 256, 0, stream>>>(wbuf, x, scalev, shiftv, out);
}

// Round 6
// 246.507 us; speedup vs baseline: 1.3205x; 1.0266x over previous
//
#include <hip/hip_runtime.h>

typedef __bf16 bf16x8 __attribute__((ext_vector_type(8)));
typedef float floatx4 __attribute__((ext_vector_type(4)));

#define DEVI __device__ __forceinline__

DEVI unsigned short f2bf(float f) {
  union { float f; unsigned u; } v; v.f = f;
  unsigned r = v.u + 0x7FFFu + ((v.u >> 16) & 1u);
  return (unsigned short)(r >> 16);
}

DEVI void gload_lds16(const void* g, void* l) {
  __builtin_amdgcn_global_load_lds((const __attribute__((address_space(1))) void*)g,
                                   (__attribute__((address_space(3))) void*)l,
                                   16, 0, 0);
}

// ---- transpose-convert x[B,512,2048] f32 -> xt[B,2048,512] bf16 ; z==16 slice does weight prep ----
__global__ __launch_bounds__(256) void k_transpose(
    const float* __restrict__ x, unsigned short* __restrict__ xt,
    const float* __restrict__ phi_w, const float* __restrict__ g_w,
    const float* __restrict__ theta_w, const float* __restrict__ W_w,
    const float* __restrict__ phi_b, const float* __restrict__ g_b,
    unsigned short* __restrict__ wpg, unsigned short* __restrict__ thw,
    unsigned short* __restrict__ ww, float* __restrict__ pgbias) {
  const int t = threadIdx.x;
  if (blockIdx.z == 16) {
    const int T0 = 512 * 512, T1 = T0 + 256 * 512, T2 = T1 + 512 * 256, T3 = T2 + 512;
    int base = (blockIdx.y * 32 + blockIdx.x) * 256 + t;
    for (int i = base; i < T3; i += 65536) {
      if (i < T0) {
        int o = i >> 9, c = i & 511;
        float v = (o < 256) ? phi_w[o * 512 + c] : g_w[(o - 256) * 512 + c];
        wpg[i] = f2bf(v);
      } else if (i < T1) {
        int j = i - T0; thw[j] = f2bf(theta_w[j]);
      } else if (i < T2) {
        int j = i - T1; ww[j] = f2bf(W_w[j]);
      } else {
        int o = i - T2; pgbias[o] = (o < 256) ? phi_b[o] : g_b[o - 256];
      }
    }
    return;
  }
  __shared__ float tile[64][65];
  const int b = blockIdx.z, c0 = blockIdx.y * 64, n0 = blockIdx.x * 64;
  const float* xb = x + (size_t)b * 512 * 2048;
#pragma unroll
  for (int i = 0; i < 16; ++i) {
    int lin = i * 256 + t;
    int lc = lin >> 6, ln = lin & 63;
    tile[lc][ln] = xb[(size_t)(c0 + lc) * 2048 + (n0 + ln)];
  }
  __syncthreads();
  unsigned short* xtb = xt + (size_t)b * 2048 * 512;
#pragma unroll
  for (int i = 0; i < 16; ++i) {
    int lin = i * 256 + t;
    int ln = lin >> 6, lc = lin & 63;
    xtb[(size_t)(n0 + ln) * 512 + (c0 + lc)] = f2bf(tile[lc][ln]);
  }
}

// ---- shared GEMM tile body: C[i,j] = scale*sum_k A[i,k]B[j,k] (+bias); BK=64, swizzled LDS ----
// EPI: 0 none, 1 +bias[row], 2 +bias[col].
template <int BM, int BN, int EPI>
DEVI void gemm_body(const unsigned short* __restrict__ Az,
                    const unsigned short* __restrict__ Bz,
                    unsigned short* __restrict__ Cz, int N, int K,
                    int row0, int col0,
                    const float* __restrict__ bias, float scale,
                    __bf16* At, __bf16* Bt) {
  constexpr int WM = BM / 2, WN = BN / 2;
  constexpr int FM = WM / 16, FN = WN / 16;
  const int t = threadIdx.x;
  const int w = t >> 6, lane = t & 63;
  const int l16 = lane & 15, lq = lane >> 4;
  const int wrow0 = (w >> 1) * WM, wcol0 = (w & 1) * WN;
  const int xorb = (l16 & 7) << 4;
  const int aoff0 = (wrow0 + l16) * 128;
  const int boff0 = (wcol0 + l16) * 128;

  floatx4 acc[FM][FN];
#pragma unroll
  for (int m = 0; m < FM; ++m)
#pragma unroll
    for (int n = 0; n < FN; ++n) acc[m][n] = (floatx4){0.f, 0.f, 0.f, 0.f};

  const int kt_end = K >> 6;
  for (int kt = 0; kt < kt_end; ++kt) {
    __syncthreads();
#pragma unroll
    for (int i = 0; i < BM * 8 / 256; ++i) {
      int ch = i * 256 + t;
      int r = ch >> 3;
      int sc = ((((ch & 7) << 4) ^ ((r & 7) << 4)) >> 1);
      gload_lds16(Az + (size_t)(row0 + r) * K + (kt << 6) + sc, &At[ch * 8]);
    }
#pragma unroll
    for (int i = 0; i < BN * 8 / 256; ++i) {
      int ch = i * 256 + t;
      int r = ch >> 3;
      int sc = ((((ch & 7) << 4) ^ ((r & 7) << 4)) >> 1);
      gload_lds16(Bz + (size_t)(col0 + r) * K + (kt << 6) + sc, &Bt[ch * 8]);
    }
    __syncthreads();

#pragma unroll
    for (int kk = 0; kk < 2; ++kk) {
      const int ck = ((kk << 6) + (lq << 4)) ^ xorb;
      bf16x8 af[FM], bq[FN];
#pragma unroll
      for (int m = 0; m < FM; ++m)
        af[m] = *(const bf16x8*)((const char*)At + aoff0 + m * 2048 + ck);
#pragma unroll
      for (int n = 0; n < FN; ++n)
        bq[n] = *(const bf16x8*)((const char*)Bt + boff0 + n * 2048 + ck);
#pragma unroll
      for (int m = 0; m < FM; ++m)
#pragma unroll
        for (int n = 0; n < FN; ++n)
          acc[m][n] = __builtin_amdgcn_mfma_f32_16x16x32_bf16(af[m], bq[n], acc[m][n], 0, 0, 0);
    }
  }

#pragma unroll
  for (int m = 0; m < FM; ++m)
#pragma unroll
    for (int n = 0; n < FN; ++n) {
      int gc = col0 + wcol0 + n * 16 + l16;
      float bc = (EPI == 2) ? bias[gc] : 0.f;
#pragma unroll
      for (int r = 0; r < 4; ++r) {
        int gr = row0 + wrow0 + m * 16 + lq * 4 + r;
        float v = acc[m][n][r] * scale;
        if (EPI == 1) v += bias[gr];
        if (EPI == 2) v += bc;
        Cz[(size_t)gr * N + gc] = f2bf(v);
      }
    }
}

// ---- fused G1+G2: grid (96, 1, 16). tid<64: PhG tile; tid>=64: Th^T tile ----
__global__ __launch_bounds__(256) void k_proj(
    const unsigned short* __restrict__ wpg, const unsigned short* __restrict__ xt,
    const unsigned short* __restrict__ thw,
    unsigned short* __restrict__ phg, unsigned short* __restrict__ tht,
    const float* __restrict__ pgbias, const float* __restrict__ theta_b) {
  __shared__ __align__(16) __bf16 At[128 * 64];
  __shared__ __align__(16) __bf16 Bt[128 * 64];
  const int z = blockIdx.z, tid = blockIdx.x;
  const size_t sXT = (size_t)2048 * 512;
  const size_t sPG = (size_t)512 * 2048;
  const size_t sTH = (size_t)2048 * 256;
  if (tid < 64) {
    // G1: PhG[o,n] = sum_c wpg[o,c] xt[n,c] + pgbias[o]  (M=512,N=2048,K=512)
    const int col = tid & 15, row = tid >> 4;
    gemm_body<128, 128, 1>(wpg, xt + z * sXT, phg + z * sPG, 2048, 512,
                           row * 128, col * 128, pgbias, 1.f, At, Bt);
  } else {
    // G2: tht[n,o] = sum_c xt[n,c] thw[o,c] + theta_b[o]  (M=2048,N=256,K=512)
    const int u = tid - 64;
    const int col = u & 1, row = u >> 1;
    gemm_body<128, 128, 2>(xt + z * sXT, thw, tht + z * sTH, 256, 512,
                           row * 128, col * 128, theta_b, 1.f, At, Bt);
  }
}

// ---- standalone GEMM (G5) ----
template <int BM, int BN, int EPI>
__global__ __launch_bounds__(256) void k_gemm(
    const unsigned short* __restrict__ A, const unsigned short* __restrict__ B,
    unsigned short* __restrict__ C, int N, int K,
    size_t sA, size_t sB, size_t sC,
    const float* __restrict__ bias, float scale) {
  __shared__ __align__(16) __bf16 At[BM * 64];
  __shared__ __align__(16) __bf16 Bt[BN * 64];
  const int z = blockIdx.z;
  gemm_body<BM, BN, EPI>(A + (size_t)z * sA, B + (size_t)z * sB, C + (size_t)z * sC,
                         N, K, blockIdx.y * BM, blockIdx.x * BN, bias, scale, At, Bt);
}

// ---- G3: pbuf[s][b][c'][c] = partial_{K-slice s} sum_n ph[c',n] g[c,n]  (NO atomics) ----
__global__ __launch_bounds__(256) void k_gemm_part(const unsigned short* __restrict__ phg,
                                                   float* __restrict__ pbuf) {
  __shared__ __align__(16) __bf16 At[128 * 64];
  __shared__ __align__(16) __bf16 Bt[128 * 64];
  const int t = threadIdx.x;
  const int tid = blockIdx.x, b = blockIdx.z;
  const int split = tid >> 2, tr = (tid >> 1) & 1, tc = tid & 1;
  const int row0 = tr * 128, col0 = tc * 128;
  const size_t sPG = (size_t)512 * 2048;
  const unsigned short* Az = phg + (size_t)b * sPG + (size_t)row0 * 2048;
  const unsigned short* Bz = phg + (size_t)b * sPG + (size_t)(256 + col0) * 2048;
  const int w = t >> 6, lane = t & 63;
  const int l16 = lane & 15, lq = lane >> 4;
  const int wrow0 = (w >> 1) * 64, wcol0 = (w & 1) * 64;
  const int xorb = (l16 & 7) << 4;
  const int aoff0 = (wrow0 + l16) * 128;
  const int boff0 = (wcol0 + l16) * 128;

  floatx4 acc[4][4];
#pragma unroll
  for (int m = 0; m < 4; ++m)
#pragma unroll
    for (int n = 0; n < 4; ++n) acc[m][n] = (floatx4){0.f, 0.f, 0.f, 0.f};

  for (int kt8 = 0; kt8 < 8; ++kt8) {
    const int kt = split * 8 + kt8;
    __syncthreads();
#pragma unroll
    for (int i = 0; i < 4; ++i) {
      int ch = i * 256 + t;
      int r = ch >> 3;
      int sc = ((((ch & 7) << 4) ^ ((r & 7) << 4)) >> 1);
      gload_lds16(Az + (size_t)r * 2048 + (kt << 6) + sc, &At[ch * 8]);
    }
#pragma unroll
    for (int i = 0; i < 4; ++i) {
      int ch = i * 256 + t;
      int r = ch >> 3;
      int sc = ((((ch & 7) << 4) ^ ((r & 7) << 4)) >> 1);
      gload_lds16(Bz + (size_t)r * 2048 + (kt << 6) + sc, &Bt[ch * 8]);
    }
    __syncthreads();
#pragma unroll
    for (int kk = 0; kk < 2; ++kk) {
      const int ck = ((kk << 6) + (lq << 4)) ^ xorb;
      bf16x8 af[4], bq[4];
#pragma unroll
      for (int m = 0; m < 4; ++m)
        af[m] = *(const bf16x8*)((const char*)At + aoff0 + m * 2048 + ck);
#pragma unroll
      for (int n = 0; n < 4; ++n)
        bq[n] = *(const bf16x8*)((const char*)Bt + boff0 + n * 2048 + ck);
#pragma unroll
      for (int m = 0; m < 4; ++m)
#pragma unroll
        for (int n = 0; n < 4; ++n)
          acc[m][n] = __builtin_amdgcn_mfma_f32_16x16x32_bf16(af[m], bq[n], acc[m][n], 0, 0, 0);
    }
  }
  float* outp = pbuf + ((size_t)split * 16 + b) * 65536;
#pragma unroll
  for (int m = 0; m < 4; ++m)
#pragma unroll
    for (int n = 0; n < 4; ++n)
#pragma unroll
      for (int r = 0; r < 4; ++r) {
        int gr = row0 + wrow0 + m * 16 + lq * 4 + r;
        int gc = col0 + wcol0 + n * 16 + l16;
        outp[(size_t)gr * 256 + gc] = acc[m][n][r];
      }
}

// ---- G4: mmat[b][co,c'] = (1/N) sum_ch ww[co,ch] (sum_s pbuf[s][b][c',ch]) ----
__global__ __launch_bounds__(256) void k_gemm_f32b(const unsigned short* __restrict__ ww,
                                                   const float* __restrict__ pbuf,
                                                   unsigned short* __restrict__ mmat) {
  __shared__ __align__(16) __bf16 At[64 * 32];
  __shared__ __align__(16) __bf16 Bt[64 * 32];
  const int t = threadIdx.x;
  const int b = blockIdx.z;
  const int col0 = blockIdx.x * 64;
  const int row0 = blockIdx.y * 64;
  const size_t SSTR = (size_t)16 * 65536;
  const float* Bz = pbuf + (size_t)b * 65536;
  const int w = t >> 6, lane = t & 63;
  const int l16 = lane & 15, lq = lane >> 4;
  const int wrow0 = (w >> 1) * 32, wcol0 = (w & 1) * 32;

  floatx4 acc[2][2];
#pragma unroll
  for (int m = 0; m < 2; ++m)
#pragma unroll
    for (int n = 0; n < 2; ++n) acc[m][n] = (floatx4){0.f, 0.f, 0.f, 0.f};

  for (int kt = 0; kt < 8; ++kt) {
    __syncthreads();
    {
      int r = t >> 2, kq = t & 3;
      gload_lds16(ww + (size_t)(row0 + r) * 256 + (kt << 5) + (kq << 3), &At[t * 8]);
    }
    {
      int r = t >> 2, kq = t & 3;
      const float* src = Bz + (size_t)(col0 + r) * 256 + (kt << 5) + (kq << 3);
      float4 a = *(const float4*)src;
      float4 c = *(const float4*)(src + 4);
#pragma unroll
      for (int s = 1; s < 4; ++s) {
        float4 a2 = *(const float4*)(src + s * SSTR);
        float4 c2 = *(const float4*)(src + s * SSTR + 4);
        a.x += a2.x; a.y += a2.y; a.z += a2.z; a.w += a2.w;
        c.x += c2.x; c.y += c2.y; c.z += c2.z; c.w += c2.w;
      }
      union { unsigned short s[8]; bf16x8 v; } pk;
      pk.s[0] = f2bf(a.x); pk.s[1] = f2bf(a.y); pk.s[2] = f2bf(a.z); pk.s[3] = f2bf(a.w);
      pk.s[4] = f2bf(c.x); pk.s[5] = f2bf(c.y); pk.s[6] = f2bf(c.z); pk.s[7] = f2bf(c.w);
      *(bf16x8*)&Bt[t * 8] = pk.v;
    }
    __syncthreads();
    bf16x8 af[2], bq[2];
#pragma unroll
    for (int m = 0; m < 2; ++m)
      af[m] = *(const bf16x8*)&At[(wrow0 + m * 16 + l16) * 32 + lq * 8];
#pragma unroll
    for (int n = 0; n < 2; ++n)
      bq[n] = *(const bf16x8*)&Bt[(wcol0 + n * 16 + l16) * 32 + lq * 8];
#pragma unroll
    for (int m = 0; m < 2; ++m)
#pragma unroll
      for (int n = 0; n < 2; ++n)
        acc[m][n] = __builtin_amdgcn_mfma_f32_16x16x32_bf16(af[m], bq[n], acc[m][n], 0, 0, 0);
  }
  unsigned short* Cz = mmat + (size_t)b * 512 * 256;
  const float scale = 1.f / 2048.f;
#pragma unroll
  for (int m = 0; m < 2; ++m)
#pragma unroll
    for (int n = 0; n < 2; ++n)
#pragma unroll
      for (int r = 0; r < 4; ++r) {
        int gr = row0 + wrow0 + m * 16 + lq * 4 + r;
        int gc = col0 + wcol0 + n * 16 + l16;
        Cz[(size_t)gr * 256 + gc] = f2bf(acc[m][n][r] * scale);
      }
}

// ---- BN stats ----
__global__ __launch_bounds__(256) void k_bnstats(const unsigned short* __restrict__ w,
                                                 const float* __restrict__ gamma,
                                                 const float* __restrict__ beta,
                                                 float* __restrict__ scale,
                                                 float* __restrict__ shift) {
  const int c = blockIdx.x, t = threadIdx.x;
  float s = 0.f, ss = 0.f;
  for (int b = 0; b < 16; ++b) {
    const unsigned short* p = w + ((size_t)b * 512 + c) * 2048 + t * 8;
    uint4 v = *(const uint4*)p;
    unsigned u[4] = {v.x, v.y, v.z, v.w};
#pragma unroll
    for (int j = 0; j < 4; ++j) {
      union { unsigned q; float f; } a, bb;
      a.q = u[j] << 16;
      bb.q = u[j] & 0xFFFF0000u;
      s += a.f + bb.f;
      ss += a.f * a.f + bb.f * bb.f;
    }
  }
#pragma unroll
  for (int off = 32; off; off >>= 1) {
    s += __shfl_down(s, off);
    ss += __shfl_down(ss, off);
  }
  __shared__ float ls[4], lss[4];
  if ((t & 63) == 0) { ls[t >> 6] = s; lss[t >> 6] = ss; }
  __syncthreads();
  if (t == 0) {
    float S = ls[0] + ls[1] + ls[2] + ls[3];
    float SS = lss[0] + lss[1] + lss[2] + lss[3];
    const float inv = 1.f / 32768.f;
    float mean = S * inv;
    float var = SS * inv - mean * mean;
    float rs = rsqrtf(var + 1e-5f);
    float sc = gamma[c] * rs;
    scale[c] = sc;
    shift[c] = beta[c] - mean * sc;
  }
}

// ---- finalize: out = w*scale[c] + shift[c] + x ----
__global__ __launch_bounds__(256) void k_final(const unsigned short* __restrict__ w,
                                               const float* __restrict__ x,
                                               const float* __restrict__ scale,
                                               const float* __restrict__ shift,
                                               float* __restrict__ out) {
  const size_t total4 = (size_t)16 * 512 * 2048 / 4;
  size_t stride = (size_t)gridDim.x * 256;
  for (size_t i = (size_t)blockIdx.x * 256 + threadIdx.x; i < total4; i += stride) {
    size_t e = i * 4;
    int c = (int)((e >> 11) & 511);
    float sc = scale[c], sh = shift[c];
    uint2 wv = *(const uint2*)(w + e);
    float4 xv = *(const float4*)(x + e);
    float4 o;
    union { unsigned q; float f; } a;
    a.q = wv.x << 16;          o.x = a.f * sc + sh + xv.x;
    a.q = wv.x & 0xFFFF0000u;  o.y = a.f * sc + sh + xv.y;
    a.q = wv.y << 16;          o.z = a.f * sc + sh + xv.z;
    a.q = wv.y & 0xFFFF0000u;  o.w = a.f * sc + sh + xv.w;
    *(float4*)(out + e) = o;
  }
}

extern "C" void kernel_launch(void* const* d_in, const int* in_sizes, int n_in,
                              void* d_out, int out_size, void* d_ws, size_t ws_size,
                              hipStream_t stream) {
  const float* x       = (const float*)d_in[0];
  const float* theta_w = (const float*)d_in[1];
  const float* theta_b = (const float*)d_in[2];
  const float* phi_w   = (const float*)d_in[3];
  const float* phi_b   = (const float*)d_in[4];
  const float* g_w     = (const float*)d_in[5];
  const float* g_b     = (const float*)d_in[6];
  const float* W_w     = (const float*)d_in[7];
  const float* W_b     = (const float*)d_in[8];
  const float* gamma   = (const float*)d_in[9];
  const float* beta    = (const float*)d_in[10];
  float* out = (float*)d_out;

  char* ws = (char*)d_ws;
  size_t off = 0;
  auto alloc = [&](size_t bytes) {
    char* p = ws + off;
    off = (off + bytes + 255) & ~(size_t)255;
    return p;
  };
  unsigned short* xt    = (unsigned short*)alloc((size_t)16 * 2048 * 512 * 2);
  unsigned short* phg   = (unsigned short*)alloc((size_t)16 * 512 * 2048 * 2);
  unsigned short* tht   = (unsigned short*)alloc((size_t)16 * 2048 * 256 * 2);
  float*          pbuf  = (float*)alloc((size_t)4 * 16 * 256 * 256 * 4);
  unsigned short* mmat  = (unsigned short*)alloc((size_t)16 * 512 * 256 * 2);
  unsigned short* wbuf  = (unsigned short*)alloc((size_t)16 * 512 * 2048 * 2);
  unsigned short* wpg   = (unsigned short*)alloc((size_t)512 * 512 * 2);
  unsigned short* thw   = (unsigned short*)alloc((size_t)256 * 512 * 2);
  unsigned short* ww    = (unsigned short*)alloc((size_t)512 * 256 * 2);
  float* pgbias         = (float*)alloc(512 * 4);
  float* scalev         = (float*)alloc(512 * 4);
  float* shiftv         = (float*)alloc(512 * 4);
  (void)ws_size; (void)in_sizes; (void)n_in; (void)out_size;

  const size_t sMM = (size_t)512 * 256;
  const size_t sTH = (size_t)2048 * 256;
  const size_t sW  = (size_t)512 * 2048;

  k_transpose<<<dim3(32, 8, 17), 256, 0, stream>>>(x, xt, phi_w, g_w, theta_w, W_w,
                                                   phi_b, g_b, wpg, thw, ww, pgbias);

  // G1+G2 fused: PhG and Th^T from xt
  k_proj<<<dim3(96, 1, 16), 256, 0, stream>>>(wpg, xt, thw, phg, tht, pgbias, theta_b);
  // G3: pbuf[s][b] = K-slice partials of Ph·G^T  (no atomics)
  k_gemm_part<<<dim3(16, 1, 16), 256, 0, stream>>>(phg, pbuf);
  // G4: mmat[co,c'] = (1/N) sum_ch ww[co,ch] (sum_s pbuf[s][c',ch])
  k_gemm_f32b<<<dim3(4, 8, 16), 256, 0, stream>>>(ww, pbuf, mmat);
  // G5: w[co,n] = sum_c' mmat[co,c'] tht[n,c'] + W_b[co]  (M=512,N=2048,K=256)
  k_gemm<128, 128, 1><<<dim3(16, 4, 16), 256, 0, stream>>>(
      mmat, tht, wbuf, 2048, 256, sMM, sTH, sW, W_b, 1.f);

  k_bnstats<<<512, 256, 0, stream>>>(wbuf, gamma, beta, scalev, shiftv);
  k_final<<<4096, 256, 0, stream>>>(wbuf, x, scalev, shiftv, out);
}